// Round 8
// baseline (113.444 us; speedup 1.0000x reference)
//
#include <hip/hip_runtime.h>
#include <hip/hip_bf16.h>
#include <cstdint>
#include <cstddef>

// Problem dims
#define SEQ 2048
#define DMODEL 1024
#define NHEAD 16
#define HDIM 64
#define MTOT 4096      // B*S
#define NQKV 3072
#define KDIM 1024

// d_out layout (floats): a[4194304] | k[4194304] | v[4194304]
#define OUT_K_BASE  4194304u
#define OUT_V_BASE  8388608u

// 0.125 * log2(e): folded into Q so QK^T scores are already in exp2 domain
#define QSCALE 0.18033688011112043f

typedef __attribute__((ext_vector_type(4))) float f32x4;
typedef __attribute__((ext_vector_type(8))) __bf16 bf16x8;
typedef __attribute__((ext_vector_type(8))) short s16x8;
typedef __attribute__((ext_vector_type(4))) short s16x4;
typedef __attribute__((ext_vector_type(2))) int i32x2;

static __device__ __forceinline__ unsigned short f2bf(float f) {
  unsigned int u = __builtin_bit_cast(unsigned int, f);
  u += 0x7FFFu + ((u >> 16) & 1u);
  return (unsigned short)(u >> 16);
}

static __device__ __forceinline__ s16x4 pack4(float4 v) {
  s16x4 r;
  r[0] = (short)f2bf(v.x);
  r[1] = (short)f2bf(v.y);
  r[2] = (short)f2bf(v.z);
  r[3] = (short)f2bf(v.w);
  return r;
}

// packed 2x f32 -> 2x bf16 in one dword (elem0 = lo)
static __device__ __forceinline__ int cvtpk(float lo, float hi) {
  int r;
  asm("v_cvt_pk_bf16_f32 %0, %1, %2" : "=v"(r) : "v"(lo), "v"(hi));
  return r;
}

static __device__ __forceinline__ f32x4 mfma16(s16x8 a, s16x8 b, f32x4 c) {
  return __builtin_amdgcn_mfma_f32_16x16x32_bf16(
      __builtin_bit_cast(bf16x8, a), __builtin_bit_cast(bf16x8, b), c, 0, 0, 0);
}

// async global->LDS, 16B per lane. LDS dest: wave-uniform base + lane*16.
static __device__ __forceinline__ void gload16(const void* g, void* l) {
  __builtin_amdgcn_global_load_lds(
      (const __attribute__((address_space(1))) unsigned int*)(uintptr_t)g,
      (__attribute__((address_space(3))) unsigned int*)(uintptr_t)l,
      16, 0, 0);
}

// counted vmcnt waits (T4): never drain to 0 in the main loop
#define WAITVM(n) asm volatile("s_waitcnt vmcnt(" #n ")" ::: "memory")

// ---------------------------------------------------------------------------
// Pre-pass: X (fp32 [4096][1024]) -> Xbf (bf16, same layout)
// ---------------------------------------------------------------------------
__global__ __launch_bounds__(256) void convert_x(
    const float* __restrict__ X, unsigned short* __restrict__ Xbf)
{
  int i = blockIdx.x * 256 + threadIdx.x;   // float4 index, 1M total
  float4 v = reinterpret_cast<const float4*>(X)[i];
  reinterpret_cast<s16x4*>(Xbf)[i] = pack4(v);
}

// ---------------------------------------------------------------------------
// Pre-pass: W (fp32 [1024][N]) -> Wt (bf16 [N][1024]) tiled transpose via LDS
// grid = (N/64, 16)
// ---------------------------------------------------------------------------
__global__ __launch_bounds__(256) void convert_wt(
    const float* __restrict__ W, unsigned short* __restrict__ Wt, int N)
{
  __shared__ unsigned short t[64][72];
  const int n0 = blockIdx.x * 64, k0 = blockIdx.y * 64;
  const int tid = threadIdx.x;
#pragma unroll
  for (int i = 0; i < 4; ++i) {
    int f = tid + (i << 8);
    int r = f >> 4, c4 = (f & 15) << 2;
    float4 v = *reinterpret_cast<const float4*>(&W[(size_t)(k0 + r) * N + n0 + c4]);
    *reinterpret_cast<s16x4*>(&t[r][c4]) = pack4(v);
  }
  __syncthreads();
#pragma unroll
  for (int i = 0; i < 2; ++i) {
    int g = tid + (i << 8);
    int n = g >> 3, k8 = (g & 7) << 3;
    s16x8 o;
#pragma unroll
    for (int jj = 0; jj < 8; ++jj) o[jj] = (short)t[k8 + jj][n];
    *reinterpret_cast<s16x8*>(&Wt[(size_t)(n0 + n) * KDIM + k0 + k8]) = o;
  }
}

// ---------------------------------------------------------------------------
// Kernel: qkv = Xbf @ Wt^T + b; route q/k/v.
// 256x256 tile, 8 waves (2M x 4N), BK=32, double-buffered 64KB LDS.
// Counted-vmcnt 2-deep pipeline (T4): raw s_barrier, per-wave vmcnt(4)
// clears only the tile about to be consumed; prefetch stays in flight
// across barriers. s_setprio around the compute cluster (T5).
// ---------------------------------------------------------------------------
__global__ __launch_bounds__(512, 2) void qkv_gemm(
    const unsigned short* __restrict__ Xbf,  // [4096][1024] bf16
    const unsigned short* __restrict__ Wt,   // [3072][1024] bf16 (W^T)
    const float* __restrict__ Bias,          // [3072]
    float* out,                              // d_out
    unsigned short* __restrict__ Qbf)
{
  __shared__ __align__(16) unsigned short lds_a[2][256][32];  // 32 KB
  __shared__ __align__(16) unsigned short lds_b[2][256][32];  // 32 KB

  unsigned short* Kbf = (unsigned short*)out;   // a-slot scratch, 8 MiB
  unsigned short* Vt  = Kbf + 4194304;          // a-slot scratch, 8 MiB

  const int tid = threadIdx.x;
  const int lane = tid & 63;
  const int wv = tid >> 6;        // 0..7
  const int wr = wv >> 2;         // 0..1  (M half)
  const int wc = wv & 3;          // 0..3  (N quarter)
  const int m0 = blockIdx.x * 256;
  const int n0 = blockIdx.y * 256;
  const int lr = lane & 15;
  const int gq = lane >> 4;

  const f32x4 fzero = {0.f, 0.f, 0.f, 0.f};
  f32x4 acc[8][4];
#pragma unroll
  for (int i = 0; i < 8; ++i)
#pragma unroll
    for (int j = 0; j < 4; ++j) acc[i][j] = fzero;

  {
    // staging: per array 1024 chunks (256 rows x 4), 2 per thread
    const int r0 = tid >> 2;            // 0..127
    const int r1 = r0 + 128;
    const int c0 = tid & 3;
    const int sc0 = ((c0 ^ ((r0 >> 1) & 3)) << 3);
    const int sc1 = ((c0 ^ ((r1 >> 1) & 3)) << 3);
    const int ub0 = (wv << 6) << 3;
    const int ub1 = ((1 << 9) + (wv << 6)) << 3;
    // 4 gload16 per wave per stage -> vmcnt granularity 4
    auto stage = [&](int nb, int kk) {
      gload16(&Xbf[(size_t)(m0 + r0) * KDIM + kk + sc0], &lds_a[nb][0][0] + ub0);
      gload16(&Xbf[(size_t)(m0 + r1) * KDIM + kk + sc1], &lds_a[nb][0][0] + ub1);
      gload16(&Wt[(size_t)(n0 + r0) * KDIM + kk + sc0], &lds_b[nb][0][0] + ub0);
      gload16(&Wt[(size_t)(n0 + r1) * KDIM + kk + sc1], &lds_b[nb][0][0] + ub1);
    };
    stage(0, 0);
    stage(1, 32);
    for (int t = 0; t < 32; ++t) {
      // clear ONLY the tile consumed this step (oldest 4 loads)
      if (t < 31) { WAITVM(4); } else { WAITVM(0); }
      __builtin_amdgcn_s_barrier();        // buf[t&1] fully staged, all waves
      const int bufg = t & 1;
      s16x8 bfv[4];
#pragma unroll
      for (int ni = 0; ni < 4; ++ni) {
        int row = wc * 64 + ni * 16 + lr;
        bfv[ni] = *reinterpret_cast<const s16x8*>(
            &lds_b[bufg][row][(gq ^ ((row >> 1) & 3)) << 3]);
      }
      __builtin_amdgcn_s_setprio(1);
#pragma unroll
      for (int mi = 0; mi < 8; ++mi) {
        int row = wr * 128 + mi * 16 + lr;
        s16x8 af = *reinterpret_cast<const s16x8*>(
            &lds_a[bufg][row][(gq ^ ((row >> 1) & 3)) << 3]);
#pragma unroll
        for (int ni = 0; ni < 4; ++ni)
          acc[mi][ni] = mfma16(af, bfv[ni], acc[mi][ni]);
      }
      __builtin_amdgcn_s_setprio(0);
      __builtin_amdgcn_s_barrier();        // all waves done READING buf[t&1]
      if (t < 30) stage(bufg, (t + 2) << 5);
    }
  }

  const int seg = n0 >> 10;   // 0=q 1=k 2=v (block-uniform; 4 y-blocks/seg)

  if (seg == 0) {
#pragma unroll
    for (int ni = 0; ni < 4; ++ni) {
      int c = n0 + wc * 64 + ni * 16 + lr;
      float bias = Bias[c];
      int h = (c & 1023) >> 6, d = c & 63;
#pragma unroll
      for (int mi = 0; mi < 8; ++mi)
#pragma unroll
        for (int j = 0; j < 4; ++j) {
          int m = m0 + wr * 128 + mi * 16 + gq * 4 + j;
          int b = m >> 11, s = m & 2047;
          Qbf[(size_t)((b * NHEAD + h) * SEQ + s) * HDIM + d] =
              f2bf((acc[mi][ni][j] + bias) * QSCALE);
        }
    }
  } else if (seg == 1) {
#pragma unroll
    for (int ni = 0; ni < 4; ++ni) {
      int c = n0 + wc * 64 + ni * 16 + lr;
      float bias = Bias[c];
      int h = (c & 1023) >> 6, d = c & 63;
#pragma unroll
      for (int mi = 0; mi < 8; ++mi)
#pragma unroll
        for (int j = 0; j < 4; ++j) {
          int m = m0 + wr * 128 + mi * 16 + gq * 4 + j;
          int b = m >> 11, s = m & 2047;
          float val = acc[mi][ni][j] + bias;
          size_t idx = (size_t)((b * NHEAD + h) * SEQ + s) * HDIM + d;
          out[OUT_K_BASE + idx] = val;
          Kbf[idx] = f2bf(val);
        }
    }
  } else {
    // V block: fp32 present store + per-wave 64x64 LDS transpose (2 halves)
    // for coalesced Vt stores. Per-wave T region: 4096 ushorts (8KB).
    __syncthreads();   // all waves done with main-loop LDS
    unsigned short* T = (wv < 4) ? (&lds_a[0][0][0] + (wv << 12))
                                 : (&lds_b[0][0][0] + ((wv - 4) << 12));
    const int b = m0 >> 11;
    const int s0 = (m0 & 2047) + wr * 128;
    const int h = (n0 >> 6) - 32 + wc;
#pragma unroll
    for (int h2 = 0; h2 < 2; ++h2) {
#pragma unroll
      for (int ni = 0; ni < 4; ++ni) {
        int c = n0 + wc * 64 + ni * 16 + lr;
        float bias = Bias[c];
        int d_loc = ni * 16 + lr;
        int dsw = d_loc & 7;
#pragma unroll
        for (int mh = 0; mh < 4; ++mh) {
          int mi = h2 * 4 + mh;
#pragma unroll
          for (int j = 0; j < 4; ++j) {
            int s_loc = mi * 16 + gq * 4 + j;      // 0..127
            int ss = s_loc - (h2 << 6);            // 0..63 within half
            float val = acc[mi][ni][j] + bias;
            out[OUT_V_BASE +
                (size_t)((b * NHEAD + h) * SEQ + s0 + s_loc) * HDIM + d_loc] = val;
            T[d_loc * 64 + (((ss >> 3) ^ dsw) << 3) + (ss & 7)] = f2bf(val);
          }
        }
      }
      // read back transposed, coalesced 16B stores (same-wave, in-order LDS)
#pragma unroll
      for (int it = 0; it < 8; ++it) {
        int dl = (lane >> 3) + (it << 3);
        int cl = lane & 7;
        s16x8 vv = *reinterpret_cast<const s16x8*>(
            &T[dl * 64 + ((cl ^ (dl & 7)) << 3)]);
        size_t vi = (((size_t)(b * NHEAD + h) * HDIM + dl) << 11) +
                    s0 + (h2 << 6) + (cl << 3);
        *reinterpret_cast<s16x8*>(&Vt[vi]) = vv;
      }
    }
  }
}

// ---------------------------------------------------------------------------
// Kernel: out = Abf @ Wpt^T + b. 128x128 tile, 4 waves, BK=64,
// double-buffered 64KB LDS, counted-vmcnt 2-deep pipeline (8 loads/stage).
// Grid (32,8) = 256 blocks = one full-chip round.
// ---------------------------------------------------------------------------
__global__ __launch_bounds__(256) void proj_gemm(
    const unsigned short* __restrict__ Abf,  // [4096][1024] bf16
    const unsigned short* __restrict__ Wpt,  // [1024][1024] bf16 (W^T)
    const float* __restrict__ Bias,          // [1024]
    float* __restrict__ out)                 // [4096][1024] fp32
{
  __shared__ __align__(16) unsigned short lds_a[2][128][64];  // 32 KB
  __shared__ __align__(16) unsigned short lds_b[2][128][64];  // 32 KB

  const int tid = threadIdx.x;
  const int lane = tid & 63;
  const int wv = tid >> 6;
  const int wr = wv >> 1, wc = wv & 1;
  const int m0 = blockIdx.x * 128;
  const int n0 = blockIdx.y * 128;
  const int lr = lane & 15;
  const int gq = lane >> 4;

  const f32x4 fzero = {0.f, 0.f, 0.f, 0.f};
  f32x4 acc[4][4];
#pragma unroll
  for (int i = 0; i < 4; ++i)
#pragma unroll
    for (int j = 0; j < 4; ++j) acc[i][j] = fzero;

  {
    // per array 1024 chunks (128 rows x 8), 4 per thread -> 8 loads/stage
    const int r0 = tid >> 3;            // 0..31
    const int c0 = tid & 7;
    auto stage = [&](int nb, int kk) {
#pragma unroll
      for (int i = 0; i < 4; ++i) {
        int r = r0 + (i << 5);
        int sc = ((c0 ^ (r & 7)) << 3);
        int ub = (((i << 8) + (wv << 6)) << 3);
        gload16(&Abf[(size_t)(m0 + r) * KDIM + kk + sc], &lds_a[nb][0][0] + ub);
        gload16(&Wpt[(size_t)(n0 + r) * KDIM + kk + sc], &lds_b[nb][0][0] + ub);
      }
    };
    stage(0, 0);
    stage(1, 64);
    for (int t = 0; t < 16; ++t) {
      if (t < 15) { WAITVM(8); } else { WAITVM(0); }
      __builtin_amdgcn_s_barrier();
      const int bufg = t & 1;
      __builtin_amdgcn_s_setprio(1);
#pragma unroll
      for (int kf = 0; kf < 2; ++kf) {
        s16x8 bfv[4];
#pragma unroll
        for (int ni = 0; ni < 4; ++ni) {
          int row = wc * 64 + ni * 16 + lr;
          bfv[ni] = *reinterpret_cast<const s16x8*>(
              &lds_b[bufg][row][((kf * 4 + gq) ^ (row & 7)) << 3]);
        }
#pragma unroll
        for (int mi = 0; mi < 4; ++mi) {
          int row = wr * 64 + mi * 16 + lr;
          s16x8 af = *reinterpret_cast<const s16x8*>(
              &lds_a[bufg][row][((kf * 4 + gq) ^ (row & 7)) << 3]);
#pragma unroll
          for (int ni = 0; ni < 4; ++ni)
            acc[mi][ni] = mfma16(af, bfv[ni], acc[mi][ni]);
        }
      }
      __builtin_amdgcn_s_setprio(0);
      __builtin_amdgcn_s_barrier();
      if (t < 14) stage(bufg, (t + 2) << 6);
    }
  }

#pragma unroll
  for (int ni = 0; ni < 4; ++ni) {
    int c = n0 + wc * 64 + ni * 16 + lr;
    float bias = Bias[c];
#pragma unroll
    for (int mi = 0; mi < 4; ++mi) {
#pragma unroll
      for (int j = 0; j < 4; ++j) {
        int m = m0 + wr * 64 + mi * 16 + gq * 4 + j;
        out[(size_t)m * DMODEL + c] = acc[mi][ni][j] + bias;
      }
    }
  }
}

// ---------------------------------------------------------------------------
// Kernel: causal flash attention — swapped QK^T, in-register softmax,
// P routed through per-wave swizzled LDS, K=32 PV. (Unchanged from R6/R7.)
// ---------------------------------------------------------------------------
__global__ __launch_bounds__(256, 4) void attn_fwd(
    const unsigned short* __restrict__ Qbf,  // pre-scaled bf16 [bh][s][d]
    const unsigned short* __restrict__ Kbf,  // bf16 [bh][s][d]
    const unsigned short* __restrict__ Vtg,  // bf16 [bh][d][s]
    unsigned short* __restrict__ Abf)        // bf16 [b][s][D] merged heads
{
  __shared__ __align__(16) unsigned short K_lds[2][64][64];
  __shared__ __align__(16) unsigned short V_lds[2][64][64];
  __shared__ __align__(16) unsigned short P_lds[4][16][64];

  const int tid = threadIdx.x;
  const int lane = tid & 63;
  const int wv = tid >> 6;
  const int bid = blockIdx.x;
  const int qt = 31 - (bid >> 5);   // longest blocks dispatch first (LPT)
  const int bh = bid & 31;

  const int lr = lane & 15;
  const int gq = lane >> 4;

  const unsigned short* Kg = Kbf + (size_t)bh * (SEQ * HDIM);
  const unsigned short* Vg = Vtg + (size_t)bh * (SEQ * HDIM);
  const unsigned short* Qg = Qbf + (size_t)bh * (SEQ * HDIM)
                                 + (size_t)(qt * 64 + wv * 16) * HDIM;

  s16x8 qf0 = *reinterpret_cast<const s16x8*>(&Qg[lr * 64 + (gq << 3)]);
  s16x8 qf1 = *reinterpret_cast<const s16x8*>(&Qg[lr * 64 + 32 + (gq << 3)]);

  const f32x4 fzero = {0.f, 0.f, 0.f, 0.f};
  f32x4 O[4];      // O^T tile no: d = 16no+4gq+reg, q = lr
  float mrow = -1e30f, lrow = 0.f;
#pragma unroll
  for (int no = 0; no < 4; ++no) O[no] = fzero;

#define STAGE(kv0, nb)                                                        \
  {                                                                           \
    _Pragma("unroll")                                                         \
    for (int i = 0; i < 2; ++i) {                                             \
      int L = tid + (i << 8);                                                 \
      int r = L >> 3, c = L & 7;                                              \
      int cc = (c ^ (r & 7)) << 3;                                            \
      int ubase = ((i << 8) + (wv << 6)) << 3;                                \
      gload16(&Kg[(((kv0) + r) << 6) + cc], &K_lds[nb][0][0] + ubase);        \
      gload16(&Vg[((size_t)r << 11) + (kv0) + cc], &V_lds[nb][0][0] + ubase); \
    }                                                                         \
  }

  STAGE(0, 0);

  for (int t = 0; t <= qt; ++t) {
    __syncthreads();
    if (t < qt) STAGE((t + 1) * 64, (t + 1) & 1);
    const int buf = t & 1;

    // ---- S^T = K Q^T : sc[ni][reg] = S[q=lr][kv=16ni+4gq+reg] ----
    f32x4 sc[4];
#pragma unroll
    for (int ni = 0; ni < 4; ++ni) {
      int kr = ni * 16 + lr;
      int sw = kr & 7;
      s16x8 kb0 = *reinterpret_cast<const s16x8*>(&K_lds[buf][kr][(gq ^ sw) << 3]);
      s16x8 kb1 = *reinterpret_cast<const s16x8*>(&K_lds[buf][kr][((gq + 4) ^ sw) << 3]);
      f32x4 tacc = mfma16(kb0, qf0, fzero);
      sc[ni] = mfma16(kb1, qf1, tacc);
    }

    if (t == qt) {
      int qloc = wv * 16 + lr;
#pragma unroll
      for (int ni = 0; ni < 4; ++ni)
#pragma unroll
        for (int r = 0; r < 4; ++r)
          if (ni * 16 + gq * 4 + r > qloc) sc[ni][r] = -1e30f;
    }

    // ---- in-register online softmax ----
    float tmax = fmaxf(fmaxf(fmaxf(sc[0][0], sc[0][1]), fmaxf(sc[0][2], sc[0][3])),
                       fmaxf(fmaxf(sc[1][0], sc[1][1]), fmaxf(sc[1][2], sc[1][3])));
    tmax = fmaxf(tmax,
                 fmaxf(fmaxf(fmaxf(sc[2][0], sc[2][1]), fmaxf(sc[2][2], sc[2][3])),
                       fmaxf(fmaxf(sc[3][0], sc[3][1]), fmaxf(sc[3][2], sc[3][3]))));
    tmax = fmaxf(tmax, __shfl_xor(tmax, 16));
    tmax = fmaxf(tmax, __shfl_xor(tmax, 32));
    float newm = fmaxf(mrow, tmax);
    float fs = __builtin_amdgcn_exp2f(mrow - newm);
    mrow = newm;
    float rs = 0.f;
#pragma unroll
    for (int ni = 0; ni < 4; ++ni) {
#pragma unroll
      for (int r = 0; r < 4; ++r) {
        float p = __builtin_amdgcn_exp2f(sc[ni][r] - newm);
        sc[ni][r] = p;
        rs += p;
      }
    }
    rs += __shfl_xor(rs, 16);
    rs += __shfl_xor(rs, 32);
    lrow = lrow * fs + rs;
#pragma unroll
    for (int no = 0; no < 4; ++no) O[no] *= fs;

    // ---- P -> per-wave LDS (B-operand layout, swizzled chunks) ----
    {
      unsigned short* Prow = &P_lds[wv][lr][0];
      const int swl = lr & 7;
#pragma unroll
      for (int ni = 0; ni < 4; ++ni) {
        i32x2 d2;
        d2[0] = cvtpk(sc[ni][0], sc[ni][1]);
        d2[1] = cvtpk(sc[ni][2], sc[ni][3]);
        int off = ((((2 * ni) + (gq >> 1)) ^ swl) << 3) + ((gq & 1) << 2);
        *reinterpret_cast<i32x2*>(&Prow[off]) = d2;
      }
      s16x8 pB0 = *reinterpret_cast<const s16x8*>(&Prow[(gq ^ swl) << 3]);
      s16x8 pB1 = *reinterpret_cast<const s16x8*>(&Prow[((gq + 4) ^ swl) << 3]);

#pragma unroll
      for (int no = 0; no < 4; ++no) {
        int dr = no * 16 + lr;
        int sw = dr & 7;
        s16x8 vb0 = *reinterpret_cast<const s16x8*>(&V_lds[buf][dr][(gq ^ sw) << 3]);
        s16x8 vb1 = *reinterpret_cast<const s16x8*>(&V_lds[buf][dr][((gq + 4) ^ sw) << 3]);
        O[no] = mfma16(vb0, pB0, O[no]);
        O[no] = mfma16(vb1, pB1, O[no]);
      }
    }
  }

  const int b = bh >> 4, h = bh & 15;
  float inv = 1.0f / lrow;
  int srow = qt * 64 + wv * 16 + lr;
  size_t base = (size_t)(b * SEQ + srow) * DMODEL + h * 64 + (gq << 2);
#pragma unroll
  for (int no = 0; no < 4; ++no) {
    s16x4 ov;
#pragma unroll
    for (int r = 0; r < 4; ++r) ov[r] = (short)f2bf(O[no][r] * inv);
    *reinterpret_cast<s16x4*>(&Abf[base + no * 16]) = ov;
  }
#undef STAGE
}

// ---------------------------------------------------------------------------
extern "C" void kernel_launch(void* const* d_in, const int* in_sizes, int n_in,
                              void* d_out, int out_size, void* d_ws, size_t ws_size,
                              hipStream_t stream) {
  const float* x        = (const float*)d_in[0];
  const float* c_attn_w = (const float*)d_in[1];
  const float* c_attn_b = (const float*)d_in[2];
  const float* c_proj_w = (const float*)d_in[3];
  const float* c_proj_b = (const float*)d_in[4];
  float* out = (float*)d_out;

  // ws layout (ushort units):
  //  [0 .. 4M)   Qbf
  //  [4M .. 8M)  Xbf (qkv) / Abf (attn+proj)  aliased by liveness
  //  [8M .. 11M) Wt (qkv) / Wpt (proj)        aliased by liveness
  unsigned short* Qbf = (unsigned short*)d_ws;
  unsigned short* Xbf = Qbf + 4194304;
  unsigned short* Abf = Xbf;
  unsigned short* Wt  = Qbf + 8388608;
  unsigned short* Wpt = Wt;
  unsigned short* Kbf = (unsigned short*)out;  // a-slot scratch
  unsigned short* Vt  = Kbf + 4194304;

  convert_x<<<dim3(4096), 256, 0, stream>>>(x, Xbf);
  convert_wt<<<dim3(48, 16), 256, 0, stream>>>(c_attn_w, Wt, NQKV);
  qkv_gemm<<<dim3(16, 12), 512, 0, stream>>>(Xbf, Wt, c_attn_b, out, Qbf);
  convert_wt<<<dim3(16, 16), 256, 0, stream>>>(c_proj_w, Wpt, DMODEL);
  attn_fwd<<<dim3(1024), 256, 0, stream>>>(Qbf, Kbf, Vt, Abf);
  proj_gemm<<<dim3(32, 8), 256, 0, stream>>>(Abf, Wpt, c_proj_b, out);
}